// Round 1
// baseline (561.254 us; speedup 1.0000x reference)
//
#include <hip/hip_runtime.h>

#define HM_W 256
#define HM_H 256
#define THRESH 0.4f

__global__ void vis_heatmap_kernel(const float* __restrict__ coords,
                                   const float* __restrict__ heat,
                                   float* __restrict__ out,
                                   int n) {  // n = B*K
    int i = blockIdx.x * blockDim.x + threadIdx.x;
    if (i >= n) return;

    float2 c = reinterpret_cast<const float2*>(coords)[i];
    float px = (c.x + 1.0f) * 0.5f * (float)HM_W;   // u -> column
    float py = (c.y + 1.0f) * 0.5f * (float)HM_H;   // v -> row
    int u = (int)px;  // trunc toward zero, matches astype(int32)
    int v = (int)py;

    bool valid = (u > -1) && (v > -1) && (v < HM_H) && (u < HM_W);
    int uc = min(max(u, 0), HM_W - 1);
    int vc = min(max(v, 0), HM_H - 1);

    float val = heat[(size_t)i * (HM_H * HM_W) + (size_t)(vc * HM_W + uc)];
    float m = (valid && (val > THRESH)) ? 1.0f : 0.0f;

    reinterpret_cast<float2*>(out)[i] = make_float2(m, m);
}

extern "C" void kernel_launch(void* const* d_in, const int* in_sizes, int n_in,
                              void* d_out, int out_size, void* d_ws, size_t ws_size,
                              hipStream_t stream) {
    const float* coords = (const float*)d_in[0];   // [B, K, 2] fp32
    const float* heat   = (const float*)d_in[1];   // [B, K, H, W] fp32
    float* out = (float*)d_out;                    // [B, K, 2] fp32

    int n = in_sizes[0] / 2;  // B*K
    int block = 256;
    int grid = (n + block - 1) / block;
    vis_heatmap_kernel<<<grid, block, 0, stream>>>(coords, heat, out, n);
}